// Round 1
// baseline (28305.621 us; speedup 1.0000x reference)
//
#include <hip/hip_runtime.h>
#include <math.h>

#define Bv 64
#define Tv 1024
#define INv 256
#define Hv 512

__device__ __forceinline__ float sigmoidf_(float x) {
    return 1.0f / (1.0f + __expf(-x));
}
__device__ __forceinline__ float tanhf_(float x) {
    float e2 = __expf(-2.0f * fabsf(x));
    float t = (1.0f - e2) / (1.0f + e2);
    return x >= 0.0f ? t : -t;
}

__global__ void kzero(unsigned* f) { f[blockIdx.x * 256 + threadIdx.x] = 0u; }

// Persistent LSTM kernel. Grid: 256 blocks (4 batch-groups x 64 unit-groups), 512 threads.
// Each block owns 16 batches x 8 hidden units (=32 gate rows). W slices live in registers.
// h(t) for all (b,t) is written into the y region of d_out (acts as the hs buffer).
__global__ void __launch_bounds__(512)
lstm_persist(const float* __restrict__ x, const float* __restrict__ h0,
             const float* __restrict__ c0, const float* __restrict__ W_ih,
             const float* __restrict__ W_hh, const float* __restrict__ b_ih,
             const float* __restrict__ b_hh, float* __restrict__ out,
             unsigned* __restrict__ flags)
{
    const int tid = threadIdx.x;
    const int bb  = blockIdx.x >> 6;   // batch group 0..3 (16 batches each)
    const int jj  = blockIdx.x & 63;   // unit group 0..63 (8 units each)
    const int lg  = tid >> 4;          // local gate row 0..31
    const int kc  = tid & 15;          // k-chunk 0..15

    const int gate = lg >> 3, ju = lg & 7;
    const int row_g = gate * Hv + jj * 8 + ju;   // global gate row in [0,2048)

    // LDS tiles, padded so the 16 kc-chunks land on distinct (or 2-way) banks.
    __shared__ float xs[16 * 320];    // x tile: [b][kc*20 + i], chunk 16 + pad 4
    __shared__ float hsh[16 * 576];   // h tile: [b][kc*36 + i], chunk 32 + pad 4
    __shared__ float gts[16 * 33];    // reduced gates [b][lg]

    // Persistent weight slices in registers
    float whh[32], wih[16];
#pragma unroll
    for (int q = 0; q < 8; ++q) {
        float4 v = *(const float4*)(W_hh + (size_t)row_g * Hv + kc * 32 + q * 4);
        whh[q*4+0] = v.x; whh[q*4+1] = v.y; whh[q*4+2] = v.z; whh[q*4+3] = v.w;
    }
#pragma unroll
    for (int q = 0; q < 4; ++q) {
        float4 v = *(const float4*)(W_ih + (size_t)row_g * INv + kc * 16 + q * 4);
        wih[q*4+0] = v.x; wih[q*4+1] = v.y; wih[q*4+2] = v.z; wih[q*4+3] = v.w;
    }
    const float bias = b_ih[row_g] + b_hh[row_g];

    // Cell-state registers for the update threads (tid < 128): 16 b x 8 j
    const int ub = tid >> 3, uj = tid & 7;
    const int ubg = bb * 16 + ub, ujg = jj * 8 + uj;
    float creg = 0.0f;
    if (tid < 128) creg = c0[ubg * Hv + ujg];

    float* hT = out + (size_t)Bv * Tv * Hv;
    float* cT = hT + (size_t)Bv * Hv;
    unsigned* flag_base = flags + bb * Tv;

    for (int t = 0; t < Tv; ++t) {
        // ---- stage x tile (independent of h(t-1); hides under producer lag) ----
#pragma unroll
        for (int r = 0; r < 2; ++r) {
            int f = tid + r * 512;
            int b = f >> 6, i4 = f & 63;
            float4 v = *(const float4*)(x + ((size_t)(bb*16 + b) * Tv + t) * INv + i4 * 4);
            *(float4*)(&xs[b * 320 + (i4 >> 2) * 20 + (i4 & 3) * 4]) = v;
        }
        __syncthreads();

        float acc[16];
#pragma unroll
        for (int b = 0; b < 16; ++b) acc[b] = 0.0f;

        // x-projection part (K = 16 cols per thread)
#pragma unroll
        for (int i4 = 0; i4 < 4; ++i4) {
#pragma unroll
            for (int b = 0; b < 16; ++b) {
                float4 v = *(const float4*)(&xs[b * 320 + kc * 20 + i4 * 4]);
                acc[b] += v.x*wih[i4*4+0] + v.y*wih[i4*4+1] + v.z*wih[i4*4+2] + v.w*wih[i4*4+3];
            }
        }

        // ---- wait for all 64 producers of h(t-1) in this batch group ----
        if (t > 0) {
            if (tid == 0) {
                unsigned* fp = flag_base + (t - 1);
                unsigned spins = 0;
                while (__hip_atomic_load(fp, __ATOMIC_RELAXED, __HIP_MEMORY_SCOPE_AGENT) < 64u) {
                    __builtin_amdgcn_s_sleep(1);
                    if (++spins > 100000000u) break;  // safety valve: fail loud, not hung
                }
                (void)__hip_atomic_load(fp, __ATOMIC_ACQUIRE, __HIP_MEMORY_SCOPE_AGENT);
            }
        }
        __syncthreads();

        // ---- stage h(t-1) tile (16 rows x 512) ----
#pragma unroll
        for (int r = 0; r < 4; ++r) {
            int f = tid + r * 512;
            int b = f >> 7, i4 = f & 127;
            const float* src = (t == 0)
                ? (h0 + (size_t)(bb*16 + b) * Hv)
                : (out + ((size_t)(bb*16 + b) * Tv + (t - 1)) * Hv);
            float4 v = *(const float4*)(src + i4 * 4);
            *(float4*)(&hsh[b * 576 + (i4 >> 3) * 36 + (i4 & 7) * 4]) = v;
        }
        __syncthreads();

        // recurrent part (K = 32 cols per thread)
#pragma unroll
        for (int i4 = 0; i4 < 8; ++i4) {
#pragma unroll
            for (int b = 0; b < 16; ++b) {
                float4 v = *(const float4*)(&hsh[b * 576 + kc * 36 + i4 * 4]);
                acc[b] += v.x*whh[i4*4+0] + v.y*whh[i4*4+1] + v.z*whh[i4*4+2] + v.w*whh[i4*4+3];
            }
        }

        // reduce partial dots across the 16 k-chunks (lane bits 0..3)
#pragma unroll
        for (int m = 1; m <= 8; m <<= 1) {
#pragma unroll
            for (int b = 0; b < 16; ++b) acc[b] += __shfl_xor(acc[b], m, 64);
        }
        if (kc == 0) {
#pragma unroll
            for (int b = 0; b < 16; ++b) gts[b * 33 + lg] = acc[b] + bias;
        }
        __syncthreads();

        // gate nonlinearities + state update (torch gate order i,f,g,o)
        if (tid < 128) {
            float gi = gts[ub * 33 +      uj];
            float gf = gts[ub * 33 +  8 + uj];
            float gg = gts[ub * 33 + 16 + uj];
            float go = gts[ub * 33 + 24 + uj];
            float iv = sigmoidf_(gi), fv = sigmoidf_(gf);
            float gv = tanhf_(gg),    ov = sigmoidf_(go);
            creg = fv * creg + iv * gv;
            float hv = ov * tanhf_(creg);
            out[((size_t)ubg * Tv + t) * Hv + ujg] = hv;
            if (t == Tv - 1) {
                hT[ubg * Hv + ujg] = hv;
                cT[ubg * Hv + ujg] = creg;
            }
        }
        __syncthreads();  // drains all waves' vmcnt before the release
        if (tid == 0) {
            __hip_atomic_fetch_add(flag_base + t, 1u, __ATOMIC_RELEASE, __HIP_MEMORY_SCOPE_AGENT);
        }
    }
}

// Fused LayerNorm (unbiased std, eps on std) + 1x1-conv skip, in place on the y region.
// Grid: 1024 blocks x 256 threads; each block owns 64 (b,t) rows.
__global__ void __launch_bounds__(256)
ln_skip(float* __restrict__ y, const float* __restrict__ x,
        const float* __restrict__ gamma, const float* __restrict__ beta,
        const float* __restrict__ conv_w, const float* __restrict__ conv_b)
{
    const int tid = threadIdx.x;
    const size_t r0 = (size_t)blockIdx.x * 64;

    __shared__ float xs[64 * 288];   // x tile [r][kcc*36 + i], chunk 32 + pad 4
    __shared__ float skp[64 * 33];   // skip values for the current 32-col chunk
    __shared__ float mean_s[64], sca_s[64];

    // row stats (4 lanes per row)
    {
        int r = tid >> 2, q = tid & 3;
        const float* hrow = y + (r0 + r) * Hv;
        float sum = 0.f, sq = 0.f;
#pragma unroll
        for (int i = 0; i < 32; ++i) {
            float4 v = *(const float4*)(hrow + (q + i * 4) * 4);
            sum += (v.x + v.y) + (v.z + v.w);
            sq  += v.x*v.x + v.y*v.y + v.z*v.z + v.w*v.w;
        }
        sum += __shfl_xor(sum, 1, 64); sum += __shfl_xor(sum, 2, 64);
        sq  += __shfl_xor(sq,  1, 64); sq  += __shfl_xor(sq,  2, 64);
        if (q == 0) {
            float mean = sum * (1.0f / 512.0f);
            float var  = (sq - 512.0f * mean * mean) * (1.0f / 511.0f);
            var = fmaxf(var, 0.0f);
            mean_s[r] = mean;
            sca_s[r]  = 1.0f / (sqrtf(var) + 1e-5f);   // reference: /(std + eps)
        }
    }

    // stage x tile (64 rows x 256)
#pragma unroll
    for (int i = 0; i < 16; ++i) {
        int f = tid + i * 256;
        int r = f >> 6, i4 = f & 63;
        float4 v = *(const float4*)(x + (r0 + r) * INv + i4 * 4);
        *(float4*)(&xs[r * 288 + (i4 >> 3) * 36 + (i4 & 7) * 4]) = v;
    }
    __syncthreads();

    const int c = tid >> 3, kcc = tid & 7;   // 32 cols x 8 k-chunks
    for (int cc = 0; cc < 16; ++cc) {
        const int cg = cc * 32 + c;
        float w[32];
#pragma unroll
        for (int q = 0; q < 8; ++q) {
            float4 v = *(const float4*)(conv_w + (size_t)cg * INv + kcc * 32 + q * 4);
            w[q*4+0] = v.x; w[q*4+1] = v.y; w[q*4+2] = v.z; w[q*4+3] = v.w;
        }
        float cb = conv_b[cg];
        for (int r = 0; r < 64; r += 2) {
            float a0 = 0.f, a1 = 0.f;
#pragma unroll
            for (int q = 0; q < 8; ++q) {
                float4 v0 = *(const float4*)(&xs[r * 288 + kcc * 36 + q * 4]);
                float4 v1 = *(const float4*)(&xs[(r + 1) * 288 + kcc * 36 + q * 4]);
                a0 += v0.x*w[q*4+0] + v0.y*w[q*4+1] + v0.z*w[q*4+2] + v0.w*w[q*4+3];
                a1 += v1.x*w[q*4+0] + v1.y*w[q*4+1] + v1.z*w[q*4+2] + v1.w*w[q*4+3];
            }
            a0 += __shfl_xor(a0, 1, 64); a0 += __shfl_xor(a0, 2, 64); a0 += __shfl_xor(a0, 4, 64);
            a1 += __shfl_xor(a1, 1, 64); a1 += __shfl_xor(a1, 2, 64); a1 += __shfl_xor(a1, 4, 64);
            if (kcc == 0) {
                skp[r * 33 + c]       = a0 + cb;
                skp[(r + 1) * 33 + c] = a1 + cb;
            }
        }
        __syncthreads();
        // output pass for this 32-col chunk (read h then overwrite, same thread)
#pragma unroll
        for (int i = 0; i < 8; ++i) {
            int o = tid + i * 256;
            int r = o >> 5, cl = o & 31;
            int cg2 = cc * 32 + cl;
            size_t idx = (r0 + r) * Hv + cg2;
            float h = y[idx];
            float val = sca_s[r] * gamma[cg2] * (h - mean_s[r]) + beta[cg2] + skp[r * 33 + cl];
            y[idx] = val;
        }
        __syncthreads();
    }
}

extern "C" void kernel_launch(void* const* d_in, const int* in_sizes, int n_in,
                              void* d_out, int out_size, void* d_ws, size_t ws_size,
                              hipStream_t stream) {
    const float* x      = (const float*)d_in[0];
    const float* h0     = (const float*)d_in[1];
    const float* c0     = (const float*)d_in[2];
    const float* W_ih   = (const float*)d_in[3];
    const float* W_hh   = (const float*)d_in[4];
    const float* b_ih   = (const float*)d_in[5];
    const float* b_hh   = (const float*)d_in[6];
    const float* gamma  = (const float*)d_in[7];
    const float* beta   = (const float*)d_in[8];
    const float* conv_w = (const float*)d_in[9];
    const float* conv_b = (const float*)d_in[10];
    float* out = (float*)d_out;
    unsigned* flags = (unsigned*)d_ws;   // 4 groups x 1024 steps

    kzero<<<16, 256, 0, stream>>>(flags);
    lstm_persist<<<256, 512, 0, stream>>>(x, h0, c0, W_ih, W_hh, b_ih, b_hh, out, flags);
    ln_skip<<<1024, 256, 0, stream>>>(out, x, gamma, beta, conv_w, conv_b);
}

// Round 2
// 21354.106 us; speedup vs baseline: 1.3255x; 1.3255x over previous
//
#include <hip/hip_runtime.h>
#include <math.h>

#define Bv 64
#define Tv 1024
#define INv 256
#define Hv 512

__device__ __forceinline__ float sigmoidf_(float x) {
    return 1.0f / (1.0f + __expf(-x));
}
__device__ __forceinline__ float tanhf_(float x) {
    float e2 = __expf(-2.0f * fabsf(x));
    float t = (1.0f - e2) / (1.0f + e2);
    return x >= 0.0f ? t : -t;
}

// Zero the per-producer flag slots through the coherence point (MALL), so the
// spin loop's cache-bypassing loads can never observe the 0xAA poison.
__global__ void kzero(unsigned* f) {
    __hip_atomic_store(&f[threadIdx.x], 0u, __ATOMIC_RELAXED, __HIP_MEMORY_SCOPE_AGENT);
}

// Persistent LSTM kernel. Grid: 256 blocks (4 batch-groups x 64 unit-groups), 512 threads.
// Each block owns 16 batches x 8 hidden units (=32 gate rows). W slices live in registers.
// Cross-block h exchange goes through MALL via relaxed agent-scope atomics — NO
// acquire/release (those emit buffer_inv / buffer_wbl2 and thrash L2 every step).
__global__ void __launch_bounds__(512)
lstm_persist(const float* __restrict__ x, const float* __restrict__ h0,
             const float* __restrict__ c0, const float* __restrict__ W_ih,
             const float* __restrict__ W_hh, const float* __restrict__ b_ih,
             const float* __restrict__ b_hh, float* __restrict__ out,
             unsigned* __restrict__ flags, float* __restrict__ hx)
{
    const int tid = threadIdx.x;
    const int bb  = blockIdx.x >> 6;   // batch group 0..3 (16 batches each)
    const int jj  = blockIdx.x & 63;   // unit group 0..63 (8 units each)
    const int lg  = tid >> 4;          // local gate row 0..31
    const int kc  = tid & 15;          // k-chunk 0..15

    const int gate = lg >> 3, ju = lg & 7;
    const int row_g = gate * Hv + jj * 8 + ju;   // global gate row in [0,2048)

    __shared__ float xs[16 * 320];    // x tile: [b][kc*20 + i], chunk 16 + pad 4
    __shared__ float hsh[16 * 576];   // h tile: [b][kc*36 + i], chunk 32 + pad 4
    __shared__ float gts[16 * 33];    // reduced gates [b][lg]

    // Persistent weight slices in registers
    float whh[32], wih[16];
#pragma unroll
    for (int q = 0; q < 8; ++q) {
        float4 v = *(const float4*)(W_hh + (size_t)row_g * Hv + kc * 32 + q * 4);
        whh[q*4+0] = v.x; whh[q*4+1] = v.y; whh[q*4+2] = v.z; whh[q*4+3] = v.w;
    }
#pragma unroll
    for (int q = 0; q < 4; ++q) {
        float4 v = *(const float4*)(W_ih + (size_t)row_g * INv + kc * 16 + q * 4);
        wih[q*4+0] = v.x; wih[q*4+1] = v.y; wih[q*4+2] = v.z; wih[q*4+3] = v.w;
    }
    const float bias = b_ih[row_g] + b_hh[row_g];

    // Cell-state registers for the update threads (tid < 128): 16 b x 8 j
    const int ub = tid >> 3, uj = tid & 7;
    const int ubg = bb * 16 + ub, ujg = jj * 8 + uj;
    float creg = 0.0f;
    if (tid < 128) creg = c0[ubg * Hv + ujg];

    float* hT = out + (size_t)Bv * Tv * Hv;
    float* cT = hT + (size_t)Bv * Hv;

    for (int t = 0; t < Tv; ++t) {
        // ---- stage x tile (independent of h(t-1)) — plain cached loads ----
#pragma unroll
        for (int r = 0; r < 2; ++r) {
            int f = tid + r * 512;
            int b = f >> 6, i4 = f & 63;
            float4 v = *(const float4*)(x + ((size_t)(bb*16 + b) * Tv + t) * INv + i4 * 4);
            *(float4*)(&xs[b * 320 + (i4 >> 2) * 20 + (i4 & 3) * 4]) = v;
        }
        __syncthreads();

        float acc[16];
#pragma unroll
        for (int b = 0; b < 16; ++b) acc[b] = 0.0f;

        // x-projection part (K = 16 cols per thread) — overlaps producer lag
#pragma unroll
        for (int i4 = 0; i4 < 4; ++i4) {
#pragma unroll
            for (int b = 0; b < 16; ++b) {
                float4 v = *(const float4*)(&xs[b * 320 + kc * 20 + i4 * 4]);
                acc[b] += v.x*wih[i4*4+0] + v.y*wih[i4*4+1] + v.z*wih[i4*4+2] + v.w*wih[i4*4+3];
            }
        }

        // ---- wait for all 64 producers of h(t-1): 64 lanes poll 64 flag slots ----
        if (t > 0) {
            if (tid < 64) {
                const unsigned* fp = flags + bb * 64 + tid;
                unsigned spins = 0;
                for (;;) {
                    unsigned v = __hip_atomic_load(fp, __ATOMIC_RELAXED, __HIP_MEMORY_SCOPE_AGENT);
                    if (__all(v >= (unsigned)t)) break;
                    if (++spins > (1u << 18)) break;   // fail loud, not hung
                }
            }
        }
        __syncthreads();

        // ---- stage h(t-1) tile: 16 rows x 512, via MALL (cache-bypassing loads) ----
        if (t == 0) {
#pragma unroll
            for (int r = 0; r < 4; ++r) {
                int f = tid + r * 512;
                int b = f >> 7, i4 = f & 127;
                float4 v = *(const float4*)(h0 + (size_t)(bb*16 + b) * Hv + i4 * 4);
                *(float4*)(&hsh[b * 576 + (i4 >> 3) * 36 + (i4 & 7) * 4]) = v;
            }
        } else {
            const float* hb = hx + ((size_t)((t - 1) & 1)) * (Bv * Hv) + (size_t)(bb * 16) * Hv;
#pragma unroll
            for (int r = 0; r < 16; ++r) {
                // row b = r, col i = tid (lane-consecutive -> coalesced)
                float v = __hip_atomic_load(hb + r * Hv + tid, __ATOMIC_RELAXED,
                                            __HIP_MEMORY_SCOPE_AGENT);
                hsh[r * 576 + (tid >> 5) * 36 + (tid & 31)] = v;
            }
        }
        __syncthreads();

        // recurrent part (K = 32 cols per thread)
#pragma unroll
        for (int i4 = 0; i4 < 8; ++i4) {
#pragma unroll
            for (int b = 0; b < 16; ++b) {
                float4 v = *(const float4*)(&hsh[b * 576 + kc * 36 + i4 * 4]);
                acc[b] += v.x*whh[i4*4+0] + v.y*whh[i4*4+1] + v.z*whh[i4*4+2] + v.w*whh[i4*4+3];
            }
        }

        // reduce partial dots across the 16 k-chunks (lane bits 0..3)
#pragma unroll
        for (int m = 1; m <= 8; m <<= 1) {
#pragma unroll
            for (int b = 0; b < 16; ++b) acc[b] += __shfl_xor(acc[b], m, 64);
        }
        if (kc == 0) {
#pragma unroll
            for (int b = 0; b < 16; ++b) gts[b * 33 + lg] = acc[b] + bias;
        }
        __syncthreads();

        // gate nonlinearities + state update (torch gate order i,f,g,o)
        if (tid < 128) {
            float gi = gts[ub * 33 +      uj];
            float gf = gts[ub * 33 +  8 + uj];
            float gg = gts[ub * 33 + 16 + uj];
            float go = gts[ub * 33 + 24 + uj];
            float iv = sigmoidf_(gi), fv = sigmoidf_(gf);
            float gv = tanhf_(gg),    ov = sigmoidf_(go);
            creg = fv * creg + iv * gv;
            float hv = ov * tanhf_(creg);
            out[((size_t)ubg * Tv + t) * Hv + ujg] = hv;                    // plain (cached)
            __hip_atomic_store(hx + ((size_t)(t & 1)) * (Bv * Hv) + (size_t)ubg * Hv + ujg,
                               hv, __ATOMIC_RELAXED, __HIP_MEMORY_SCOPE_AGENT);
            if (t == Tv - 1) {
                hT[ubg * Hv + ujg] = hv;
                cT[ubg * Hv + ujg] = creg;
            }
        }
        // __syncthreads drains every wave's vmcnt (store-ack at MALL) before the flag:
        // this IS the release ordering, minus the L2 flush we don't need.
        __syncthreads();
        if (tid == 0) {
            __hip_atomic_store(flags + bb * 64 + jj, (unsigned)(t + 1),
                               __ATOMIC_RELAXED, __HIP_MEMORY_SCOPE_AGENT);
        }
    }
}

// Fused LayerNorm (unbiased std, eps on std) + 1x1-conv skip, in place on the y region.
// Grid: 1024 blocks x 256 threads; each block owns 64 (b,t) rows.
__global__ void __launch_bounds__(256)
ln_skip(float* __restrict__ y, const float* __restrict__ x,
        const float* __restrict__ gamma, const float* __restrict__ beta,
        const float* __restrict__ conv_w, const float* __restrict__ conv_b)
{
    const int tid = threadIdx.x;
    const size_t r0 = (size_t)blockIdx.x * 64;

    __shared__ float xs[64 * 288];   // x tile [r][kcc*36 + i], chunk 32 + pad 4
    __shared__ float skp[64 * 33];   // skip values for the current 32-col chunk
    __shared__ float mean_s[64], sca_s[64];

    // row stats (4 lanes per row)
    {
        int r = tid >> 2, q = tid & 3;
        const float* hrow = y + (r0 + r) * Hv;
        float sum = 0.f, sq = 0.f;
#pragma unroll
        for (int i = 0; i < 32; ++i) {
            float4 v = *(const float4*)(hrow + (q + i * 4) * 4);
            sum += (v.x + v.y) + (v.z + v.w);
            sq  += v.x*v.x + v.y*v.y + v.z*v.z + v.w*v.w;
        }
        sum += __shfl_xor(sum, 1, 64); sum += __shfl_xor(sum, 2, 64);
        sq  += __shfl_xor(sq,  1, 64); sq  += __shfl_xor(sq,  2, 64);
        if (q == 0) {
            float mean = sum * (1.0f / 512.0f);
            float var  = (sq - 512.0f * mean * mean) * (1.0f / 511.0f);
            var = fmaxf(var, 0.0f);
            mean_s[r] = mean;
            sca_s[r]  = 1.0f / (sqrtf(var) + 1e-5f);   // reference: /(std + eps)
        }
    }

    // stage x tile (64 rows x 256)
#pragma unroll
    for (int i = 0; i < 16; ++i) {
        int f = tid + i * 256;
        int r = f >> 6, i4 = f & 63;
        float4 v = *(const float4*)(x + (r0 + r) * INv + i4 * 4);
        *(float4*)(&xs[r * 288 + (i4 >> 3) * 36 + (i4 & 7) * 4]) = v;
    }
    __syncthreads();

    const int c = tid >> 3, kcc = tid & 7;   // 32 cols x 8 k-chunks
    for (int cc = 0; cc < 16; ++cc) {
        const int cg = cc * 32 + c;
        float w[32];
#pragma unroll
        for (int q = 0; q < 8; ++q) {
            float4 v = *(const float4*)(conv_w + (size_t)cg * INv + kcc * 32 + q * 4);
            w[q*4+0] = v.x; w[q*4+1] = v.y; w[q*4+2] = v.z; w[q*4+3] = v.w;
        }
        float cb = conv_b[cg];
        for (int r = 0; r < 64; r += 2) {
            float a0 = 0.f, a1 = 0.f;
#pragma unroll
            for (int q = 0; q < 8; ++q) {
                float4 v0 = *(const float4*)(&xs[r * 288 + kcc * 36 + q * 4]);
                float4 v1 = *(const float4*)(&xs[(r + 1) * 288 + kcc * 36 + q * 4]);
                a0 += v0.x*w[q*4+0] + v0.y*w[q*4+1] + v0.z*w[q*4+2] + v0.w*w[q*4+3];
                a1 += v1.x*w[q*4+0] + v1.y*w[q*4+1] + v1.z*w[q*4+2] + v1.w*w[q*4+3];
            }
            a0 += __shfl_xor(a0, 1, 64); a0 += __shfl_xor(a0, 2, 64); a0 += __shfl_xor(a0, 4, 64);
            a1 += __shfl_xor(a1, 1, 64); a1 += __shfl_xor(a1, 2, 64); a1 += __shfl_xor(a1, 4, 64);
            if (kcc == 0) {
                skp[r * 33 + c]       = a0 + cb;
                skp[(r + 1) * 33 + c] = a1 + cb;
            }
        }
        __syncthreads();
        // output pass for this 32-col chunk (read h then overwrite, same thread)
#pragma unroll
        for (int i = 0; i < 8; ++i) {
            int o = tid + i * 256;
            int r = o >> 5, cl = o & 31;
            int cg2 = cc * 32 + cl;
            size_t idx = (r0 + r) * Hv + cg2;
            float h = y[idx];
            float val = sca_s[r] * gamma[cg2] * (h - mean_s[r]) + beta[cg2] + skp[r * 33 + cl];
            y[idx] = val;
        }
        __syncthreads();
    }
}

extern "C" void kernel_launch(void* const* d_in, const int* in_sizes, int n_in,
                              void* d_out, int out_size, void* d_ws, size_t ws_size,
                              hipStream_t stream) {
    const float* x      = (const float*)d_in[0];
    const float* h0     = (const float*)d_in[1];
    const float* c0     = (const float*)d_in[2];
    const float* W_ih   = (const float*)d_in[3];
    const float* W_hh   = (const float*)d_in[4];
    const float* b_ih   = (const float*)d_in[5];
    const float* b_hh   = (const float*)d_in[6];
    const float* gamma  = (const float*)d_in[7];
    const float* beta   = (const float*)d_in[8];
    const float* conv_w = (const float*)d_in[9];
    const float* conv_b = (const float*)d_in[10];
    float* out = (float*)d_out;

    unsigned* flags = (unsigned*)d_ws;                    // 4 groups x 64 producers
    float*    hx    = (float*)((char*)d_ws + 4096);       // double-buffered h exchange [2][64][512]

    kzero<<<1, 256, 0, stream>>>(flags);
    lstm_persist<<<256, 512, 0, stream>>>(x, h0, c0, W_ih, W_hh, b_ih, b_hh, out, flags, hx);
    ln_skip<<<1024, 256, 0, stream>>>(out, x, gamma, beta, conv_w, conv_b);
}